// Round 5
// baseline (78.651 us; speedup 1.0000x reference)
//
#include <hip/hip_runtime.h>

// ResidualVQ forward: out[n] = codebook[argmin_k(-2 x.c_k + ||c_k||^2)]
// v5: codebook pre-split (hi/lo bf16) and pre-permuted into MFMA B-fragment
// order in d_ws by a pre-kernel. Main kernel: pure global_load_lds staging
// (linear, zero VALU, zero conflicts) + 48 MFMA/tile + verified margin
// candidate list + exact fp32 recheck. BR=64, 512 blocks -> 2 blocks/CU.

typedef short bfrag __attribute__((ext_vector_type(8)));  // 8 bf16 = 4 VGPR
typedef float f32x4 __attribute__((ext_vector_type(4)));

constexpr int D = 128;       // embedding dim
constexpr int BR = 64;       // rows per block -> 512 blocks = 2 blocks/CU
constexpr int NTH = 256;     // 4 waves: 2 row-groups x 2 code-halves
constexpr int TC = 64;       // codes per LDS tile
constexpr int NTILE = 16;    // 1024 / 64
constexpr int LCAP = 2048;
#define MARGIN 0.0625f

__device__ __forceinline__ unsigned fenc(float f) {  // order-preserving f32->u32
    unsigned u = __float_as_uint(f);
    return (u & 0x80000000u) ? ~u : (u | 0x80000000u);
}
__device__ __forceinline__ float fdec(unsigned e) {
    unsigned u = (e & 0x80000000u) ? (e & 0x7FFFFFFFu) : ~e;
    return __uint_as_float(u);
}
__device__ __forceinline__ unsigned cvtpk(float a, float b) {
    unsigned r;
    asm("v_cvt_pk_bf16_f32 %0, %1, %2" : "=v"(r) : "v"(a), "v"(b));
    return r;
}
union FU { bfrag v; unsigned u[4]; };

// 8 fp32 -> bf16 hi fragment + bf16 lo (residual) fragment
__device__ __forceinline__ void conv8(const float* f, bfrag& hi, bfrag& lo) {
    FU h, l;
#pragma unroll
    for (int m = 0; m < 4; ++m) {
        float a = f[2 * m], b = f[2 * m + 1];
        unsigned hp = cvtpk(a, b);
        float ra = a - __uint_as_float(hp << 16);
        float rb = b - __uint_as_float(hp & 0xFFFF0000u);
        h.u[m] = hp;
        l.u[m] = cvtpk(ra, rb);
    }
    hi = h.v;
    lo = l.v;
}

// --- kernel 0: codebook squared norms ---
__global__ __launch_bounds__(256) void cnorm_kernel(const float* __restrict__ cb,
                                                    float* __restrict__ cnorm, int K) {
    int k = blockIdx.x * blockDim.x + threadIdx.x;
    if (k >= K) return;
    const float4* c = (const float4*)(cb + (size_t)k * D);
    float s0 = 0.f, s1 = 0.f, s2 = 0.f, s3 = 0.f;
#pragma unroll
    for (int i = 0; i < D / 4; ++i) {
        float4 v = c[i];
        s0 = fmaf(v.x, v.x, s0);
        s1 = fmaf(v.y, v.y, s1);
        s2 = fmaf(v.z, v.z, s2);
        s3 = fmaf(v.w, v.w, s3);
    }
    cnorm[k] = (s0 + s1) + (s2 + s3);
}

// --- kernel 1: split codebook into hi/lo bf16, permuted to B-fragment order.
// Fragment t (= cg*256 + ks*64 + lane, lane = kg*16+la) holds
// cb[cg*16+la][ks*32+kg*8 .. +7]. Flat 16B write at offset t*16 (coalesced).
__global__ __launch_bounds__(256) void split_cb_kernel(const float* __restrict__ cb,
                                                       short* __restrict__ hi,
                                                       short* __restrict__ lo) {
    const int t = blockIdx.x * 256 + threadIdx.x;  // 0..16383
    const int cg = t >> 8;
    const int r = t & 255;
    const int ks = r >> 6;
    const int lane = r & 63;
    const int kg = lane >> 4, la = lane & 15;
    const float* src = cb + (size_t)(cg * 16 + la) * D + ks * 32 + kg * 8;
    float4 f0 = *(const float4*)src;
    float4 f1 = *(const float4*)(src + 4);
    float v[8] = {f0.x, f0.y, f0.z, f0.w, f1.x, f1.y, f1.z, f1.w};
    bfrag h, l;
    conv8(v, h, l);
    ((bfrag*)hi)[t] = h;
    ((bfrag*)lo)[t] = l;
}

__global__ __launch_bounds__(NTH, 2) void vq_mfma(const float* __restrict__ x,
                                                  const float* __restrict__ cb,
                                                  const short* __restrict__ cbh,
                                                  const short* __restrict__ cbl,
                                                  const float* __restrict__ cnorm,
                                                  float* __restrict__ out,
                                                  int N, int K) {
    __shared__ short hib[2][TC * D];     // 2 x 16 KB, fragment-linear
    __shared__ short lob[2][TC * D];     // 2 x 16 KB
    __shared__ float cns[1024];
    __shared__ unsigned rmin[BR];
    __shared__ unsigned long long win[BR];
    __shared__ unsigned clist[LCAP];
    __shared__ int ccnt;

    const int tid = threadIdx.x;
    const int lane = tid & 63;
    const int wv = tid >> 6;   // 0..3
    const int rg = wv >> 1;    // row-group (32 rows each)
    const int ch = wv & 1;     // code half of tile (32 codes)
    const int la = lane & 15;
    const int kg = lane >> 4;
    const int row0 = blockIdx.x * BR;

    if (tid < BR) { rmin[tid] = 0xFF7FFFFFu; win[tid] = ~0ull; }
    if (tid == 0) ccnt = 0;
    for (int i = tid; i < K; i += NTH) cns[i] = cnorm[i];

    // ---- x -> split-bf16 A-fragments in registers (row=la, k=kg*8+j) ----
    bfrag xh[2][4], xl[2][4];
#pragma unroll
    for (int rf = 0; rf < 2; ++rf) {
        const int xrow = row0 + rg * 32 + rf * 16 + la;
        const float* xp = x + (size_t)xrow * D + kg * 8;
#pragma unroll
        for (int ks = 0; ks < 4; ++ks) {
            float4 f0 = *(const float4*)(xp + ks * 32);
            float4 f1 = *(const float4*)(xp + ks * 32 + 4);
            float v[8] = {f0.x, f0.y, f0.z, f0.w, f1.x, f1.y, f1.z, f1.w};
            conv8(v, xh[rf][ks], xl[rf][ks]);
        }
    }

    // ---- pure linear tile staging: ws (fragment order) -> LDS, no VALU ----
    auto stage = [&](int t, int buf) {
        const char* gh = (const char*)cbh + (size_t)t * 16384 + wv * 4096 + lane * 16;
        const char* gl = (const char*)cbl + (size_t)t * 16384 + wv * 4096 + lane * 16;
        char* lh = (char*)&hib[buf][0] + wv * 4096;  // wave-uniform base (+lane*16 by HW)
        char* ll = (char*)&lob[buf][0] + wv * 4096;
#pragma unroll
        for (int i = 0; i < 4; ++i) {
            __builtin_amdgcn_global_load_lds(
                (const __attribute__((address_space(1))) uint32_t*)(gh + i * 1024),
                (__attribute__((address_space(3))) uint32_t*)(lh + i * 1024), 16, 0, 0);
            __builtin_amdgcn_global_load_lds(
                (const __attribute__((address_space(1))) uint32_t*)(gl + i * 1024),
                (__attribute__((address_space(3))) uint32_t*)(ll + i * 1024), 16, 0, 0);
        }
    };

    stage(0, 0);
    __syncthreads();

    for (int t = 0; t < NTILE; ++t) {
        const int buf = t & 1;
        if (t + 1 < NTILE) stage(t + 1, buf ^ 1);  // loads fly under the MFMAs

        // ---- compute: 4 ks x 2 cf x 2 rf x 3 split-terms = 48 MFMA ----
        f32x4 acc[2][2] = {{{0.f, 0.f, 0.f, 0.f}, {0.f, 0.f, 0.f, 0.f}},
                           {{0.f, 0.f, 0.f, 0.f}, {0.f, 0.f, 0.f, 0.f}}};
        const short* ph = &hib[buf][0];
        const short* pl = &lob[buf][0];
#pragma unroll
        for (int ks = 0; ks < 4; ++ks) {
            bfrag bh[2], bl[2];
#pragma unroll
            for (int cf = 0; cf < 2; ++cf) {
                const int off = (ch * 2 + cf) * 2048 + ks * 512 + lane * 8;  // shorts
                bh[cf] = *(const bfrag*)(ph + off);  // lane-linear ds_read_b128
                bl[cf] = *(const bfrag*)(pl + off);
            }
#pragma unroll
            for (int rf = 0; rf < 2; ++rf)
#pragma unroll
                for (int cf = 0; cf < 2; ++cf) {
                    acc[rf][cf] = __builtin_amdgcn_mfma_f32_16x16x32_bf16(
                        xh[rf][ks], bh[cf], acc[rf][cf], 0, 0, 0);
                    acc[rf][cf] = __builtin_amdgcn_mfma_f32_16x16x32_bf16(
                        xh[rf][ks], bl[cf], acc[rf][cf], 0, 0, 0);
                    acc[rf][cf] = __builtin_amdgcn_mfma_f32_16x16x32_bf16(
                        xl[rf][ks], bh[cf], acc[rf][cf], 0, 0, 0);
                }
        }

        // ---- epilogue (verified round 4): C/D col=la, row=kg*4+i ----
        const int c0 = t * TC + ch * 32 + la;
        const int c1 = c0 + 16;
        const float cn0 = cns[c0], cn1 = cns[c1];
#pragma unroll
        for (int rf = 0; rf < 2; ++rf) {
            float d0[4], d1[4], m[4];
#pragma unroll
            for (int i = 0; i < 4; ++i) {
                d0[i] = fmaf(-2.f, acc[rf][0][i], cn0);
                d1[i] = fmaf(-2.f, acc[rf][1][i], cn1);
                m[i] = fminf(d0[i], d1[i]);
            }
#pragma unroll
            for (int i = 0; i < 4; ++i)
#pragma unroll
                for (int off = 1; off <= 8; off <<= 1)
                    m[i] = fminf(m[i], __shfl_xor(m[i], off));
#pragma unroll
            for (int i = 0; i < 4; ++i) {
                const int row = rg * 32 + rf * 16 + kg * 4 + i;
                const float thr = fminf(fdec(rmin[row]), m[i]) + MARGIN;
                if (d0[i] < thr) {
                    int p = atomicAdd(&ccnt, 1);
                    if (p < LCAP) clist[p] = (unsigned)((row << 10) | c0);
                }
                if (d1[i] < thr) {
                    int p = atomicAdd(&ccnt, 1);
                    if (p < LCAP) clist[p] = (unsigned)((row << 10) | c1);
                }
                if (la == 0) atomicMin(&rmin[row], fenc(m[i]));
            }
        }

        __syncthreads();  // drains vmcnt: tile t+1 landed; cbt reads done
    }

    // ---- exact fp32 recheck; packed atomicMin keeps lowest index on ties ----
    const int nc = (ccnt > LCAP) ? LCAP : ccnt;
    for (int b = wv * 4 + kg; b < nc; b += 16) {  // one candidate per 16-lane group
        const unsigned e = clist[b];
        const int row = e >> 10, code = e & 1023;
        const float4* xr4 = (const float4*)(x + (size_t)(row0 + row) * D + la * 8);
        const float4* cr4 = (const float4*)(cb + (size_t)code * D + la * 8);
        float4 a0 = xr4[0], a1 = xr4[1], b0 = cr4[0], b1 = cr4[1];
        float s = a0.x * b0.x;
        s = fmaf(a0.y, b0.y, s); s = fmaf(a0.z, b0.z, s); s = fmaf(a0.w, b0.w, s);
        s = fmaf(a1.x, b1.x, s); s = fmaf(a1.y, b1.y, s);
        s = fmaf(a1.z, b1.z, s); s = fmaf(a1.w, b1.w, s);
#pragma unroll
        for (int off = 1; off <= 8; off <<= 1) s += __shfl_xor(s, off);
        const float dist = fmaf(-2.f, s, cns[code]);
        if (la == 0)
            atomicMin(&win[row], ((unsigned long long)fenc(dist) << 32) | (unsigned)code);
    }
    __syncthreads();

    // ---- gather: out[row] = cb[winner] ----
    {
        const int r = tid >> 2, q = tid & 3;
        const int idx = (int)(win[r] & 0xFFFFFFFFull);
        const float4* cs = (const float4*)(cb + (size_t)idx * D + q * 32);
        float4* od = (float4*)(out + (size_t)(row0 + r) * D + q * 32);
#pragma unroll
        for (int i = 0; i < 8; ++i) od[i] = cs[i];
    }
}

extern "C" void kernel_launch(void* const* d_in, const int* in_sizes, int n_in,
                              void* d_out, int out_size, void* d_ws, size_t ws_size,
                              hipStream_t stream) {
    const float* x = (const float*)d_in[0];
    const float* cb = (const float*)d_in[1];
    float* out = (float*)d_out;
    const int N = in_sizes[0] / D;   // 32768
    const int K = in_sizes[1] / D;   // 1024

    float* cnorm = (float*)d_ws;                              // 4 KB
    short* cbh = (short*)((char*)d_ws + 4096);                // 256 KB
    short* cbl = (short*)((char*)d_ws + 4096 + 262144);       // 256 KB

    hipLaunchKernelGGL(cnorm_kernel, dim3((K + 255) / 256), dim3(256), 0, stream,
                       cb, cnorm, K);
    hipLaunchKernelGGL(split_cb_kernel, dim3(64), dim3(256), 0, stream, cb, cbh, cbl);
    hipLaunchKernelGGL(vq_mfma, dim3(N / BR), dim3(NTH), 0, stream,
                       x, cb, cbh, cbl, cnorm, out, N, K);
}

// Round 6
// 66.856 us; speedup vs baseline: 1.1764x; 1.1764x over previous
//
#include <hip/hip_runtime.h>

// ResidualVQ forward: out[n] = codebook[argmin_k(-2 x.c_k + ||c_k||^2)]
// v6: same verified datapath as v5 (pre-split/pre-permuted codebook in d_ws,
// linear global_load_lds staging, 3-term split-bf16 MFMA, margin candidate
// list + exact fp32 recheck) restructured for occupancy: 8 waves/block of
// 16 rows x 32 codes each, 2 blocks/CU -> 4 waves/SIMD (was 2).

typedef short bfrag __attribute__((ext_vector_type(8)));  // 8 bf16 = 4 VGPR
typedef float f32x4 __attribute__((ext_vector_type(4)));

constexpr int D = 128;       // embedding dim
constexpr int BR = 64;       // rows per block -> 512 blocks
constexpr int NTH = 512;     // 8 waves: 4 row-groups (16 rows) x 2 code-halves
constexpr int TC = 64;       // codes per LDS tile
constexpr int NTILE = 16;    // 1024 / 64
constexpr int LCAP = 512;    // candidate list capacity (expect ~67)
#define MARGIN 0.0625f

__device__ __forceinline__ unsigned fenc(float f) {  // order-preserving f32->u32
    unsigned u = __float_as_uint(f);
    return (u & 0x80000000u) ? ~u : (u | 0x80000000u);
}
__device__ __forceinline__ float fdec(unsigned e) {
    unsigned u = (e & 0x80000000u) ? (e & 0x7FFFFFFFu) : ~e;
    return __uint_as_float(u);
}
__device__ __forceinline__ unsigned cvtpk(float a, float b) {
    unsigned r;
    asm("v_cvt_pk_bf16_f32 %0, %1, %2" : "=v"(r) : "v"(a), "v"(b));
    return r;
}
union FU { bfrag v; unsigned u[4]; };

// 8 fp32 -> bf16 hi fragment + bf16 lo (residual) fragment
__device__ __forceinline__ void conv8(const float* f, bfrag& hi, bfrag& lo) {
    FU h, l;
#pragma unroll
    for (int m = 0; m < 4; ++m) {
        float a = f[2 * m], b = f[2 * m + 1];
        unsigned hp = cvtpk(a, b);
        float ra = a - __uint_as_float(hp << 16);
        float rb = b - __uint_as_float(hp & 0xFFFF0000u);
        h.u[m] = hp;
        l.u[m] = cvtpk(ra, rb);
    }
    hi = h.v;
    lo = l.v;
}

// --- kernel 0: codebook squared norms ---
__global__ __launch_bounds__(256) void cnorm_kernel(const float* __restrict__ cb,
                                                    float* __restrict__ cnorm, int K) {
    int k = blockIdx.x * blockDim.x + threadIdx.x;
    if (k >= K) return;
    const float4* c = (const float4*)(cb + (size_t)k * D);
    float s0 = 0.f, s1 = 0.f, s2 = 0.f, s3 = 0.f;
#pragma unroll
    for (int i = 0; i < D / 4; ++i) {
        float4 v = c[i];
        s0 = fmaf(v.x, v.x, s0);
        s1 = fmaf(v.y, v.y, s1);
        s2 = fmaf(v.z, v.z, s2);
        s3 = fmaf(v.w, v.w, s3);
    }
    cnorm[k] = (s0 + s1) + (s2 + s3);
}

// --- kernel 1: split codebook into hi/lo bf16, permuted to B-fragment order.
// Fragment t (= cg*256 + ks*64 + lane, lane = kg*16+la) holds
// cb[cg*16+la][ks*32+kg*8 .. +7]. Flat 16B write at offset t*16 (coalesced).
__global__ __launch_bounds__(256) void split_cb_kernel(const float* __restrict__ cb,
                                                       short* __restrict__ hi,
                                                       short* __restrict__ lo) {
    const int t = blockIdx.x * 256 + threadIdx.x;  // 0..16383
    const int cg = t >> 8;
    const int r = t & 255;
    const int ks = r >> 6;
    const int lane = r & 63;
    const int kg = lane >> 4, la = lane & 15;
    const float* src = cb + (size_t)(cg * 16 + la) * D + ks * 32 + kg * 8;
    float4 f0 = *(const float4*)src;
    float4 f1 = *(const float4*)(src + 4);
    float v[8] = {f0.x, f0.y, f0.z, f0.w, f1.x, f1.y, f1.z, f1.w};
    bfrag h, l;
    conv8(v, h, l);
    ((bfrag*)hi)[t] = h;
    ((bfrag*)lo)[t] = l;
}

__global__ __launch_bounds__(NTH, 4) void vq_mfma(const float* __restrict__ x,
                                                  const float* __restrict__ cb,
                                                  const short* __restrict__ cbh,
                                                  const short* __restrict__ cbl,
                                                  const float* __restrict__ cnorm,
                                                  float* __restrict__ out,
                                                  int N, int K) {
    __shared__ short hib[2][TC * D];     // 2 x 16 KB, fragment-linear
    __shared__ short lob[2][TC * D];     // 2 x 16 KB
    __shared__ float cns[1024];          // 4 KB
    __shared__ unsigned rmin[BR];
    __shared__ unsigned long long win[BR];
    __shared__ unsigned clist[LCAP];     // 2 KB
    __shared__ int ccnt;
    // total ~70.8 KB -> 2 blocks/CU = 16 waves/CU = 4 waves/SIMD

    const int tid = threadIdx.x;
    const int lane = tid & 63;
    const int wv = tid >> 6;   // 0..7
    const int rg = wv >> 1;    // row-group (16 rows each)
    const int ch = wv & 1;     // code half of tile (32 codes)
    const int la = lane & 15;
    const int kg = lane >> 4;
    const int row0 = blockIdx.x * BR;

    if (tid < BR) { rmin[tid] = 0xFF7FFFFFu; win[tid] = ~0ull; }
    if (tid == 0) ccnt = 0;
    for (int i = tid; i < K; i += NTH) cns[i] = cnorm[i];

    // ---- x -> split-bf16 A-fragments in registers (row=la, k=kg*8+j) ----
    bfrag xh[4], xl[4];
    {
        const int xrow = row0 + rg * 16 + la;
        const float* xp = x + (size_t)xrow * D + kg * 8;
#pragma unroll
        for (int ks = 0; ks < 4; ++ks) {
            float4 f0 = *(const float4*)(xp + ks * 32);
            float4 f1 = *(const float4*)(xp + ks * 32 + 4);
            float v[8] = {f0.x, f0.y, f0.z, f0.w, f1.x, f1.y, f1.z, f1.w};
            conv8(v, xh[ks], xl[ks]);
        }
    }

    // ---- pure linear tile staging: ws (fragment order) -> LDS, no VALU ----
    auto stage = [&](int t, int buf) {
        const char* gh = (const char*)cbh + (size_t)t * 16384 + wv * 2048 + lane * 16;
        const char* gl = (const char*)cbl + (size_t)t * 16384 + wv * 2048 + lane * 16;
        char* lh = (char*)&hib[buf][0] + wv * 2048;  // wave-uniform base (+lane*16 by HW)
        char* ll = (char*)&lob[buf][0] + wv * 2048;
#pragma unroll
        for (int i = 0; i < 2; ++i) {
            __builtin_amdgcn_global_load_lds(
                (const __attribute__((address_space(1))) uint32_t*)(gh + i * 1024),
                (__attribute__((address_space(3))) uint32_t*)(lh + i * 1024), 16, 0, 0);
            __builtin_amdgcn_global_load_lds(
                (const __attribute__((address_space(1))) uint32_t*)(gl + i * 1024),
                (__attribute__((address_space(3))) uint32_t*)(ll + i * 1024), 16, 0, 0);
        }
    };

    stage(0, 0);
    __syncthreads();

    for (int t = 0; t < NTILE; ++t) {
        const int buf = t & 1;
        if (t + 1 < NTILE) stage(t + 1, buf ^ 1);  // loads fly under the MFMAs

        // ---- compute: 4 ks x 2 cf x 3 split-terms = 24 MFMA/wave ----
        f32x4 acc[2] = {{0.f, 0.f, 0.f, 0.f}, {0.f, 0.f, 0.f, 0.f}};
        const short* ph = &hib[buf][0];
        const short* pl = &lob[buf][0];
#pragma unroll
        for (int ks = 0; ks < 4; ++ks) {
            bfrag bh[2], bl[2];
#pragma unroll
            for (int cf = 0; cf < 2; ++cf) {
                const int off = (ch * 2 + cf) * 2048 + ks * 512 + lane * 8;  // shorts
                bh[cf] = *(const bfrag*)(ph + off);  // lane-linear ds_read_b128
                bl[cf] = *(const bfrag*)(pl + off);
            }
#pragma unroll
            for (int cf = 0; cf < 2; ++cf) {
                acc[cf] = __builtin_amdgcn_mfma_f32_16x16x32_bf16(
                    xh[ks], bh[cf], acc[cf], 0, 0, 0);
                acc[cf] = __builtin_amdgcn_mfma_f32_16x16x32_bf16(
                    xh[ks], bl[cf], acc[cf], 0, 0, 0);
                acc[cf] = __builtin_amdgcn_mfma_f32_16x16x32_bf16(
                    xl[ks], bh[cf], acc[cf], 0, 0, 0);
            }
        }

        // ---- epilogue (verified r4/r5): C/D col=la, row=kg*4+i ----
        const int c0 = t * TC + ch * 32 + la;
        const int c1 = c0 + 16;
        const float cn0 = cns[c0], cn1 = cns[c1];
        {
            float d0[4], d1[4], m[4];
#pragma unroll
            for (int i = 0; i < 4; ++i) {
                d0[i] = fmaf(-2.f, acc[0][i], cn0);
                d1[i] = fmaf(-2.f, acc[1][i], cn1);
                m[i] = fminf(d0[i], d1[i]);
            }
#pragma unroll
            for (int i = 0; i < 4; ++i)
#pragma unroll
                for (int off = 1; off <= 8; off <<= 1)
                    m[i] = fminf(m[i], __shfl_xor(m[i], off));
#pragma unroll
            for (int i = 0; i < 4; ++i) {
                const int row = rg * 16 + kg * 4 + i;
                // stale-high rowmin is safe (superset append); m[i] covers this tile
                const float thr = fminf(fdec(rmin[row]), m[i]) + MARGIN;
                if (d0[i] < thr) {
                    int p = atomicAdd(&ccnt, 1);
                    if (p < LCAP) clist[p] = (unsigned)((row << 10) | c0);
                }
                if (d1[i] < thr) {
                    int p = atomicAdd(&ccnt, 1);
                    if (p < LCAP) clist[p] = (unsigned)((row << 10) | c1);
                }
                if (la == 0) atomicMin(&rmin[row], fenc(m[i]));
            }
        }

        __syncthreads();  // drains vmcnt: tile t+1 landed; LDS reads done
    }

    // ---- exact fp32 recheck; packed atomicMin keeps lowest index on ties ----
    const int nc = (ccnt > LCAP) ? LCAP : ccnt;
    for (int b = wv * 4 + kg; b < nc; b += 32) {  // one candidate per 16-lane group
        const unsigned e = clist[b];
        const int row = e >> 10, code = e & 1023;
        const float4* xr4 = (const float4*)(x + (size_t)(row0 + row) * D + la * 8);
        const float4* cr4 = (const float4*)(cb + (size_t)code * D + la * 8);
        float4 a0 = xr4[0], a1 = xr4[1], b0 = cr4[0], b1 = cr4[1];
        float s = a0.x * b0.x;
        s = fmaf(a0.y, b0.y, s); s = fmaf(a0.z, b0.z, s); s = fmaf(a0.w, b0.w, s);
        s = fmaf(a1.x, b1.x, s); s = fmaf(a1.y, b1.y, s);
        s = fmaf(a1.z, b1.z, s); s = fmaf(a1.w, b1.w, s);
#pragma unroll
        for (int off = 1; off <= 8; off <<= 1) s += __shfl_xor(s, off);
        const float dist = fmaf(-2.f, s, cns[code]);
        if (la == 0)
            atomicMin(&win[row], ((unsigned long long)fenc(dist) << 32) | (unsigned)code);
    }
    __syncthreads();

    // ---- gather: out[row] = cb[winner] (coalesced float4) ----
    {
        const int r = tid >> 3, q = tid & 7;  // 64 rows x 8 chunks of 16 floats
        const int idx = (int)(win[r] & 0xFFFFFFFFull);
        const float4* cs = (const float4*)(cb + (size_t)idx * D + q * 16);
        float4* od = (float4*)(out + (size_t)(row0 + r) * D + q * 16);
#pragma unroll
        for (int i = 0; i < 4; ++i) od[i] = cs[i];
    }
}

extern "C" void kernel_launch(void* const* d_in, const int* in_sizes, int n_in,
                              void* d_out, int out_size, void* d_ws, size_t ws_size,
                              hipStream_t stream) {
    const float* x = (const float*)d_in[0];
    const float* cb = (const float*)d_in[1];
    float* out = (float*)d_out;
    const int N = in_sizes[0] / D;   // 32768
    const int K = in_sizes[1] / D;   // 1024

    float* cnorm = (float*)d_ws;                              // 4 KB
    short* cbh = (short*)((char*)d_ws + 4096);                // 256 KB
    short* cbl = (short*)((char*)d_ws + 4096 + 262144);       // 256 KB

    hipLaunchKernelGGL(cnorm_kernel, dim3((K + 255) / 256), dim3(256), 0, stream,
                       cb, cnorm, K);
    hipLaunchKernelGGL(split_cb_kernel, dim3(64), dim3(256), 0, stream, cb, cbh, cbl);
    hipLaunchKernelGGL(vq_mfma, dim3(N / BR), dim3(NTH), 0, stream,
                       x, cb, cbh, cbl, cnorm, out, N, K);
}

// Round 7
// 53.522 us; speedup vs baseline: 1.4695x; 1.2491x over previous
//
#include <hip/hip_runtime.h>

// ResidualVQ forward: out[n] = codebook[argmin_k(-2 x.c_k + ||c_k||^2)]
// v7: swapped-operand MFMA (codes on C-rows, x-rows on C-cols -> lane-local
// row argmin), cn folded in via acc-init of (-2x)-scaled GEMM, codebook kept
// bf16-hi only (x stays split hi+lo; MARGIN=3.25 provably covers |x . cb_lo|).
// LDS ~39 KB -> 4 blocks/CU target. Margin candidate list + exact fp32 recheck.

typedef short bfrag __attribute__((ext_vector_type(8)));  // 8 bf16 = 4 VGPR
typedef float f32x4 __attribute__((ext_vector_type(4)));

constexpr int D = 128;       // embedding dim
constexpr int BR = 64;       // rows per block -> 512 blocks
constexpr int NTH = 512;     // 8 waves: 4 row-groups (16 rows) x 2 code-halves
constexpr int TC = 64;       // codes per LDS tile
constexpr int NTILE = 16;    // 1024 / 64
constexpr int LCAP = 640;    // candidate capacity (expect ~200-350 worst)
#define MARGIN 3.25f         // > 2 * max dist err (1.57, Cauchy-Schwarz bound)

__device__ __forceinline__ unsigned fenc(float f) {  // order-preserving f32->u32
    unsigned u = __float_as_uint(f);
    return (u & 0x80000000u) ? ~u : (u | 0x80000000u);
}
__device__ __forceinline__ float fdec(unsigned e) {
    unsigned u = (e & 0x80000000u) ? (e & 0x7FFFFFFFu) : ~e;
    return __uint_as_float(u);
}
__device__ __forceinline__ unsigned cvtpk(float a, float b) {
    unsigned r;
    asm("v_cvt_pk_bf16_f32 %0, %1, %2" : "=v"(r) : "v"(a), "v"(b));
    return r;
}
union FU { bfrag v; unsigned u[4]; };

// 8 fp32 -> bf16 hi fragment + bf16 lo (residual) fragment
__device__ __forceinline__ void conv8(const float* f, bfrag& hi, bfrag& lo) {
    FU h, l;
#pragma unroll
    for (int m = 0; m < 4; ++m) {
        float a = f[2 * m], b = f[2 * m + 1];
        unsigned hp = cvtpk(a, b);
        float ra = a - __uint_as_float(hp << 16);
        float rb = b - __uint_as_float(hp & 0xFFFF0000u);
        h.u[m] = hp;
        l.u[m] = cvtpk(ra, rb);
    }
    hi = h.v;
    lo = l.v;
}

// --- kernel 0: codebook squared norms (exact fp32) ---
__global__ __launch_bounds__(256) void cnorm_kernel(const float* __restrict__ cb,
                                                    float* __restrict__ cnorm, int K) {
    int k = blockIdx.x * blockDim.x + threadIdx.x;
    if (k >= K) return;
    const float4* c = (const float4*)(cb + (size_t)k * D);
    float s0 = 0.f, s1 = 0.f, s2 = 0.f, s3 = 0.f;
#pragma unroll
    for (int i = 0; i < D / 4; ++i) {
        float4 v = c[i];
        s0 = fmaf(v.x, v.x, s0);
        s1 = fmaf(v.y, v.y, s1);
        s2 = fmaf(v.z, v.z, s2);
        s3 = fmaf(v.w, v.w, s3);
    }
    cnorm[k] = (s0 + s1) + (s2 + s3);
}

// --- kernel 1: cast codebook to bf16 (RN), permuted to MFMA fragment order.
// Fragment t (= cg*256 + ks*64 + lane, lane = kg*16+la) holds
// cb[cg*16+la][ks*32+kg*8 .. +7]. Flat 16B write (coalesced).
__global__ __launch_bounds__(256) void cast_cb_kernel(const float* __restrict__ cb,
                                                      short* __restrict__ hi) {
    const int t = blockIdx.x * 256 + threadIdx.x;  // 0..16383
    const int cg = t >> 8;
    const int r = t & 255;
    const int ks = r >> 6;
    const int lane = r & 63;
    const int kg = lane >> 4, la = lane & 15;
    const float* src = cb + (size_t)(cg * 16 + la) * D + ks * 32 + kg * 8;
    float4 f0 = *(const float4*)src;
    float4 f1 = *(const float4*)(src + 4);
    FU h;
    h.u[0] = cvtpk(f0.x, f0.y);
    h.u[1] = cvtpk(f0.z, f0.w);
    h.u[2] = cvtpk(f1.x, f1.y);
    h.u[3] = cvtpk(f1.z, f1.w);
    ((bfrag*)hi)[t] = h.v;
}

__global__ __launch_bounds__(NTH, 8) void vq_mfma(const float* __restrict__ x,
                                                  const float* __restrict__ cb,
                                                  const short* __restrict__ cbh,
                                                  const float* __restrict__ cnorm,
                                                  float* __restrict__ out,
                                                  int N, int K) {
    __shared__ short hib[2][TC * D];     // 2 x 16 KB, fragment-linear
    __shared__ float cns[1024];          // 4 KB (also acc-init source)
    __shared__ unsigned clist[LCAP];     // 2.5 KB
    __shared__ unsigned long long win[BR];
    __shared__ unsigned rmin[BR];
    __shared__ int ccnt;
    // total ~39.3 KB -> 4 blocks/CU = 32 waves/CU

    const int tid = threadIdx.x;
    const int lane = tid & 63;
    const int wv = tid >> 6;   // 0..7
    const int rg = wv >> 1;    // row-group (16 rows each)
    const int ch = wv & 1;     // code half of tile (32 codes)
    const int la = lane & 15;
    const int kg = lane >> 4;
    const int row0 = blockIdx.x * BR;

    if (tid < BR) { rmin[tid] = 0xFF7FFFFFu; win[tid] = ~0ull; }
    if (tid == 0) ccnt = 0;
    for (int i = tid; i < K; i += NTH) cns[i] = cnorm[i];

    // ---- (-2x) -> split-bf16 B-fragments in registers (col=la=row, k=kg*8+j) ----
    bfrag xh[4], xl[4];
    {
        const int xrow = row0 + rg * 16 + la;
        const float* xp = x + (size_t)xrow * D + kg * 8;
#pragma unroll
        for (int ks = 0; ks < 4; ++ks) {
            float4 f0 = *(const float4*)(xp + ks * 32);
            float4 f1 = *(const float4*)(xp + ks * 32 + 4);
            float v[8] = {-2.f * f0.x, -2.f * f0.y, -2.f * f0.z, -2.f * f0.w,
                          -2.f * f1.x, -2.f * f1.y, -2.f * f1.z, -2.f * f1.w};
            conv8(v, xh[ks], xl[ks]);
        }
    }

    // ---- pure linear tile staging: ws (fragment order) -> LDS, no VALU ----
    auto stage = [&](int t, int buf) {
        const char* gh = (const char*)cbh + (size_t)t * 16384 + wv * 2048 + lane * 16;
        char* lh = (char*)&hib[buf][0] + wv * 2048;  // wave-uniform base (+lane*16 HW)
        __builtin_amdgcn_global_load_lds(
            (const __attribute__((address_space(1))) uint32_t*)(gh),
            (__attribute__((address_space(3))) uint32_t*)(lh), 16, 0, 0);
        __builtin_amdgcn_global_load_lds(
            (const __attribute__((address_space(1))) uint32_t*)(gh + 1024),
            (__attribute__((address_space(3))) uint32_t*)(lh + 1024), 16, 0, 0);
    };

    stage(0, 0);
    __syncthreads();

    for (int t = 0; t < NTILE; ++t) {
        const int buf = t & 1;
        if (t + 1 < NTILE) stage(t + 1, buf ^ 1);  // loads fly under the MFMAs

        // ---- acc init = cns fragment (codes are fragment-linear) ----
        // code(cf,i) = t*64 + ch*32 + cf*16 + kg*4 + i
        const int cbase = t * TC + ch * 32;
        f32x4 acc[2];
        acc[0] = *(const f32x4*)&cns[cbase + kg * 4];
        acc[1] = *(const f32x4*)&cns[cbase + 16 + kg * 4];

        // ---- compute: 4 ks x 2 cf x 2 terms = 16 MFMA, 8 ds_read_b128 ----
        const short* ph = &hib[buf][0];
#pragma unroll
        for (int ks = 0; ks < 4; ++ks) {
            bfrag bh[2];
#pragma unroll
            for (int cf = 0; cf < 2; ++cf) {
                const int off = (ch * 2 + cf) * 2048 + ks * 512 + lane * 8;  // shorts
                bh[cf] = *(const bfrag*)(ph + off);  // lane-linear ds_read_b128
            }
#pragma unroll
            for (int cf = 0; cf < 2; ++cf) {
                // swapped operands: A=codebook, B=x -> C[row=code][col=x-row]
                acc[cf] = __builtin_amdgcn_mfma_f32_16x16x32_bf16(
                    bh[cf], xh[ks], acc[cf], 0, 0, 0);
                acc[cf] = __builtin_amdgcn_mfma_f32_16x16x32_bf16(
                    bh[cf], xl[ks], acc[cf], 0, 0, 0);
            }
        }
        // acc[cf][i] = cn - 2 x.c  for code cbase+cf*16+kg*4+i, x-row rg*16+la

        // ---- lane-local epilogue: row-min, margin append, rmin update ----
        {
            float rowmin = fminf(fminf(fminf(acc[0][0], acc[0][1]), fminf(acc[0][2], acc[0][3])),
                                 fminf(fminf(acc[1][0], acc[1][1]), fminf(acc[1][2], acc[1][3])));
            rowmin = fminf(rowmin, __shfl_xor(rowmin, 16));
            rowmin = fminf(rowmin, __shfl_xor(rowmin, 32));  // min over all 32 codes
            const int row = rg * 16 + la;
            // stale-high rmin is safe (superset append); rowmin covers this tile
            const float thr = fminf(fdec(rmin[row]), rowmin) + MARGIN;
#pragma unroll
            for (int cf = 0; cf < 2; ++cf)
#pragma unroll
                for (int i = 0; i < 4; ++i) {
                    if (acc[cf][i] < thr) {
                        int p = atomicAdd(&ccnt, 1);
                        if (p < LCAP)
                            clist[p] = (unsigned)((row << 10) | (cbase + cf * 16 + kg * 4 + i));
                    }
                }
            if (kg == 0) atomicMin(&rmin[row], fenc(rowmin));
        }

        __syncthreads();  // drains vmcnt: tile t+1 landed; LDS reads done
    }

    // ---- exact fp32 recheck; packed atomicMin keeps lowest index on ties ----
    const int nc = (ccnt > LCAP) ? LCAP : ccnt;
    for (int b = wv * 4 + kg; b < nc; b += 32) {  // one candidate per 16-lane group
        const unsigned e = clist[b];
        const int row = e >> 10, code = e & 1023;
        const float4* xr4 = (const float4*)(x + (size_t)(row0 + row) * D + la * 8);
        const float4* cr4 = (const float4*)(cb + (size_t)code * D + la * 8);
        float4 a0 = xr4[0], a1 = xr4[1], b0 = cr4[0], b1 = cr4[1];
        float s = a0.x * b0.x;
        s = fmaf(a0.y, b0.y, s); s = fmaf(a0.z, b0.z, s); s = fmaf(a0.w, b0.w, s);
        s = fmaf(a1.x, b1.x, s); s = fmaf(a1.y, b1.y, s);
        s = fmaf(a1.z, b1.z, s); s = fmaf(a1.w, b1.w, s);
#pragma unroll
        for (int off = 1; off <= 8; off <<= 1) s += __shfl_xor(s, off);
        const float dist = fmaf(-2.f, s, cns[code]);
        if (la == 0)
            atomicMin(&win[row], ((unsigned long long)fenc(dist) << 32) | (unsigned)code);
    }
    __syncthreads();

    // ---- gather: out[row] = cb[winner] (coalesced float4) ----
    {
        const int r = tid >> 3, q = tid & 7;  // 64 rows x 8 chunks of 16 floats
        const int idx = (int)(win[r] & 0xFFFFFFFFull);
        const float4* cs = (const float4*)(cb + (size_t)idx * D + q * 16);
        float4* od = (float4*)(out + (size_t)(row0 + r) * D + q * 16);
#pragma unroll
        for (int i = 0; i < 4; ++i) od[i] = cs[i];
    }
}

extern "C" void kernel_launch(void* const* d_in, const int* in_sizes, int n_in,
                              void* d_out, int out_size, void* d_ws, size_t ws_size,
                              hipStream_t stream) {
    const float* x = (const float*)d_in[0];
    const float* cb = (const float*)d_in[1];
    float* out = (float*)d_out;
    const int N = in_sizes[0] / D;   // 32768
    const int K = in_sizes[1] / D;   // 1024

    float* cnorm = (float*)d_ws;                   // 4 KB
    short* cbh = (short*)((char*)d_ws + 4096);     // 256 KB bf16 fragments

    hipLaunchKernelGGL(cnorm_kernel, dim3((K + 255) / 256), dim3(256), 0, stream,
                       cb, cnorm, K);
    hipLaunchKernelGGL(cast_cb_kernel, dim3(64), dim3(256), 0, stream, cb, cbh);
    hipLaunchKernelGGL(vq_mfma, dim3(N / BR), dim3(NTH), 0, stream,
                       x, cb, cbh, cnorm, out, N, K);
}